// Round 5
// baseline (134.220 us; speedup 1.0000x reference)
//
#include <hip/hip_runtime.h>
#include <math.h>

// B,S,D,V,N_BLOCKS = 4096,128,9,5,4
constexpr int Bn = 4096;
constexpr int Sn = 128;
constexpr int Dn = 9;
constexpr int Vn = 5;
constexpr int NBn = 4;

typedef float f4 __attribute__((ext_vector_type(4)));
typedef _Float16 h8 __attribute__((ext_vector_type(8)));   // MFMA operand type
typedef __fp16   h2 __attribute__((ext_vector_type(2)));
typedef unsigned u4v __attribute__((ext_vector_type(4)));
typedef short s4v __attribute__((ext_vector_type(4)));

// Workspace layout (floats):
//  [it*96 + e*9 + d]  = M'[e][d] = qscale * sum_f Wk[f][e]*Wq[f][d]   (it<4, e,d<9)
//  [it*96 + 81 + d]   = w'[d]    = qscale * sum_f Wk[f][d]*bq[f]
//  [384 + r*9 + d]    = positional encoding PE[r][d]
// Softmax shift invariance: S[q][k] = x_q M x_k + w.x_k (+ per-q consts that
// cancel), so K-side needs NO projection and bk drops out entirely.
constexpr int WS_PE = 384;

// LDS layout (bytes). Row stride 80B = 20 banks (odd multiple of 4) so both
// the 4xb128 row writes and the quad frag reads spread uniformly over all
// eight 4-bank groups.
//  KF [128] rows x 32 fp16 slots [Xh(9)|Xh(9)|Xl(9)|th,tl|z3], stride 40 shorts
//  QF [128] rows x 32 fp16 slots [Yh(9)|Yl(9)|Yh(9)|1,1|z3], Y = M'^T-proj of x
//     One K=32 MFMA yields Xh*Yh + Xh*Yl + Xl*Yh + t (exact to ~2^-22).
//  VF [16][136] fp16 V^T; row 9 = 1.0 (written once) so the PV MFMA also
//     produces the softmax denominator as O^T row 9. Rows 10..15 unwritten.
//  XB [128][12] f32 inter-layer activations, stride 48B
// No-max softmax: scores bounded |s|<~12 in log2 domain; exp2 direct is safe
// (fp16 max 2^15.99) and rcp-normalization restores the exact softmax.
//
// OCCUPANCY RESTRUCTURE (R4): 512 threads / 8 waves, ONE q-tile per wave.
// Same LDS -> 4 blocks x 8 waves = 32 waves/CU (wave-slot cap = 100%) vs the
// previous 256-thread config measured at ~36% occupancy. Phase-1 work is
// split 4-ways per row (quarters: K+t | Q-fold | V[0:5) | V[5:9)).
constexpr int KF_OFF = 0;          // 10240
constexpr int QF_OFF = 10240;      // 10240
constexpr int VF_OFF = 20480;      // 16*272 = 4352
constexpr int XB_OFF = 24832;      // 6144
constexpr int SMEM_BYTES = 30976;

static __device__ __forceinline__ void split_hl(const float* v, _Float16* H, _Float16* L) {
    #pragma unroll
    for (int i = 0; i < 9; ++i) {
        _Float16 h = (_Float16)v[i];
        H[i] = h;
        L[i] = (_Float16)(v[i] - (float)h);
    }
}

static __device__ __forceinline__ unsigned pk(_Float16 a, _Float16 b) {
    h2 t; t.x = (__fp16)a; t.y = (__fp16)b;
    return __builtin_bit_cast(unsigned, t);
}

// Store one 32-slot row [X(9)|Y(9)|Z(9)|T0,T1|0,0,0] (4 x b128)
static __device__ __forceinline__ void store_row32(short* rowp,
        const _Float16* X, const _Float16* Y, const _Float16* Z,
        _Float16 T0, _Float16 T1) {
    const _Float16 z0 = (_Float16)0.0f;
    u4v w0 = (u4v){ pk(X[0],X[1]), pk(X[2],X[3]), pk(X[4],X[5]), pk(X[6],X[7]) };
    u4v w1 = (u4v){ pk(X[8],Y[0]), pk(Y[1],Y[2]), pk(Y[3],Y[4]), pk(Y[5],Y[6]) };
    u4v w2 = (u4v){ pk(Y[7],Y[8]), pk(Z[0],Z[1]), pk(Z[2],Z[3]), pk(Z[4],Z[5]) };
    u4v w3 = (u4v){ pk(Z[6],Z[7]), pk(Z[8],T0),   pk(T1,z0),     0u            };
    u4v* qp = (u4v*)rowp;
    qp[0] = w0; qp[1] = w1; qp[2] = w2; qp[3] = w3;
}

static __device__ __forceinline__ h8 read_quad(const short* base, int row, int quad) {
    return *(const h8*)(base + row * 40 + quad * 8);
}

// Tiny prep: M'/w' folds (input-only, shared by all 4096 blocks) + PE table.
__global__ void prep_kernel(const float* __restrict__ Wq, const float* __restrict__ bq,
                            const float* __restrict__ Wk, float* __restrict__ ws)
{
    const float qs = (1.0f / 3.0f) * 1.44269504f;   // 1/sqrt(D) * log2(e)
    const int idx = blockIdx.x * 256 + threadIdx.x;
    if (idx < 360) {
        const int it = idx / 90, j = idx % 90;
        const float* wq = Wq + it * 81;
        const float* wk = Wk + it * 81;
        float acc = 0.0f;
        if (j < 81) {
            const int e = j / 9, d = j % 9;
            #pragma unroll
            for (int f = 0; f < 9; ++f) acc = fmaf(wk[f * 9 + e], wq[f * 9 + d], acc);
        } else {
            const int d = j - 81;
            const float* bqp = bq + it * 9;
            #pragma unroll
            for (int f = 0; f < 9; ++f) acc = fmaf(wk[f * 9 + d], bqp[f], acc);
        }
        ws[it * 96 + j] = acc * qs;
    } else if (idx < 360 + Sn * Dn) {
        const int j = idx - 360;
        const int r = j / 9, d = j % 9;
        const float inv_freq[Dn] = {
            1.0f, 1.0f, 0.1291549665f, 0.1291549665f, 0.0166810054f,
            0.0166810054f, 0.0021544347f, 0.0021544347f, 0.0002782559f };
        const float a = (float)r * inv_freq[d];
        ws[WS_PE + j] = (d & 1) ? cosf(a) : sinf(a);
    }
}

// One block = one batch, 8 waves. Phase 1 (per row r = tid&127, quarter
// tid>>7): q0 stages raw-X K rows + bias-fold t, q1 projects Y = M'^T x,
// q2/q3 project V columns. Phase 2: wave w owns q-tile w: S^T via one
// 3-term MFMA per key-tile, exp2 direct (no max), denominator from the PV
// ones-row, O^T = V^T.P^T fp16 (4 MFMAs).
__global__ __launch_bounds__(512, 8) void bert_kernel(
    const int*   __restrict__ tokens,
    const float* __restrict__ emb,
    const float* __restrict__ Wv, const float* __restrict__ bv,
    const float* __restrict__ Wout, const float* __restrict__ bout,
    const float* __restrict__ wsp,
    float*       __restrict__ out)
{
    __shared__ __align__(16) char smem[SMEM_BYTES];
    short* KF = (short*)(smem + KF_OFF);
    short* QF = (short*)(smem + QF_OFF);
    short* VF = (short*)(smem + VF_OFF);
    float* XB = (float*)(smem + XB_OFF);

    const int b   = blockIdx.x;
    const int tid = threadIdx.x;         // 0..511
    const int t   = tid & 63;
    const int w   = tid >> 6;            // wave 0..7
    const int col = t & 15;
    const int g   = t >> 4;
    const int q4  = tid >> 7;            // phase-1 quarter 0..3
    const int r   = tid & 127;           // phase-1 row
    const float* MP = wsp;               // [4][96] M'/w'
    const float* PE = wsp + WS_PE;       // [128][9]

    // ---- stage 0: embed + positional encoding -> XB; VF ones row ----
    if (tid < 128) {
        const int tok = tokens[b * Sn + r];
        float xr[9];
        #pragma unroll
        for (int d = 0; d < Dn; ++d)
            xr[d] = emb[tok * Dn + d] + PE[r * 9 + d];
        f4* xp = (f4*)&XB[r * 12];
        xp[0] = (f4){xr[0], xr[1], xr[2], xr[3]};
        xp[1] = (f4){xr[4], xr[5], xr[6], xr[7]};
        xp[2] = (f4){xr[8], 0.0f, 0.0f, 0.0f};
    } else if (tid < 256) {
        VF[9 * 136 + r] = (short)0x3C00;   // fp16 1.0 — persists across layers
    }
    __syncthreads();

    #pragma unroll 1
    for (int it = 0; it < NBn; ++it) {
        // ---- phase 1: staging, split 4-ways per row ----
        {
            const f4* xp = (const f4*)&XB[r * 12];
            f4 a0 = xp[0], a1 = xp[1], a2 = xp[2];
            float x[9] = {a0.x, a0.y, a0.z, a0.w, a1.x, a1.y, a1.z, a1.w, a2.x};
            const float* wv  = Wv + it * 81;
            const float* bvi = bv + it * 9;
            const float* mp  = MP + it * 96;
            if (q4 == 0) {
                float tb = 0.0f;                      // t_k = w'.x (bias fold)
                #pragma unroll
                for (int d = 0; d < Dn; ++d) tb = fmaf(x[d], mp[81 + d], tb);
                _Float16 H[9], L[9];
                split_hl(x, H, L);
                _Float16 th = (_Float16)tb;
                _Float16 tl = (_Float16)(tb - (float)th);
                store_row32(KF + r * 40, H, H, L, th, tl);   // [Xh|Xh|Xl|th,tl]
            } else if (q4 == 1) {
                float y[9];                           // y = M'^T-fold of x (pre-scaled)
                #pragma unroll
                for (int e = 0; e < Dn; ++e) {
                    float a = 0.0f;
                    #pragma unroll
                    for (int d = 0; d < Dn; ++d) a = fmaf(x[d], mp[e * 9 + d], a);
                    y[e] = a;
                }
                _Float16 H[9], L[9];
                split_hl(y, H, L);
                store_row32(QF + r * 40, H, L, H,
                            (_Float16)1.0f, (_Float16)1.0f);  // [Yh|Yl|Yh|1,1]
            } else if (q4 == 2) {
                #pragma unroll
                for (int e = 0; e < 5; ++e) {
                    float av = bvi[e];
                    #pragma unroll
                    for (int d = 0; d < Dn; ++d) av = fmaf(x[d], wv[e * 9 + d], av);
                    VF[e * 136 + r] = __builtin_bit_cast(short, (_Float16)av);
                }
            } else {
                #pragma unroll
                for (int e = 5; e < Dn; ++e) {
                    float av = bvi[e];
                    #pragma unroll
                    for (int d = 0; d < Dn; ++d) av = fmaf(x[d], wv[e * 9 + d], av);
                    VF[e * 136 + r] = __builtin_bit_cast(short, (_Float16)av);
                }
            }
        }
        __syncthreads();

        // ---- phase 2: wave w owns q-tile w ----
        h8 kfr[8];
        #pragma unroll
        for (int kt = 0; kt < 8; ++kt)
            kfr[kt] = read_quad(KF, kt * 16 + col, g);

        // V^T A-frags with permuted K-dim: slot (g,j) <-> key 16*(2s+(j>>2))+4g+(j&3)
        h8 vf[4];
        #pragma unroll
        for (int s = 0; s < 4; ++s) {
            const short* p0 = VF + col * 136 + 32 * s + 4 * g;
            s4v va = *(const s4v*)p0;
            s4v vb = *(const s4v*)(p0 + 16);
            vf[s] = __builtin_bit_cast(h8,
                __builtin_shufflevector(va, vb, 0, 1, 2, 3, 4, 5, 6, 7));
        }

        const int q = w * 16 + col;
        h8 bq3 = read_quad(QF, q, g);

        f4 acc[8];
        #pragma unroll
        for (int kt = 0; kt < 8; ++kt)
            acc[kt] = __builtin_amdgcn_mfma_f32_16x16x32_f16(kfr[kt], bq3, (f4)(0.0f), 0, 0, 0);

        // lane holds S^T[key = kt*16 + 4g + rr][q] (log2 domain); exp2 direct.
        #pragma unroll
        for (int kt = 0; kt < 8; ++kt)
            #pragma unroll
            for (int rr = 0; rr < 4; ++rr)
                acc[kt][rr] = __builtin_amdgcn_exp2f(acc[kt][rr]);

        // P B-frags: slot j=0..3 -> (kt=2s, rr=j); j=4..7 -> (kt=2s+1, rr=j&3)
        f4 oac = (f4)(0.0f);
        #pragma unroll
        for (int s = 0; s < 4; ++s) {
            u4v up = (u4v){
                __builtin_bit_cast(unsigned, __builtin_amdgcn_cvt_pkrtz(acc[2*s][0],   acc[2*s][1])),
                __builtin_bit_cast(unsigned, __builtin_amdgcn_cvt_pkrtz(acc[2*s][2],   acc[2*s][3])),
                __builtin_bit_cast(unsigned, __builtin_amdgcn_cvt_pkrtz(acc[2*s+1][0], acc[2*s+1][1])),
                __builtin_bit_cast(unsigned, __builtin_amdgcn_cvt_pkrtz(acc[2*s+1][2], acc[2*s+1][3])) };
            oac = __builtin_amdgcn_mfma_f32_16x16x32_f16(vf[s], __builtin_bit_cast(h8, up), oac, 0, 0, 0);
        }
        // denominator: O^T row 9 = sum_k P[k][q], held by lane 32+q, reg 1
        const float sm = __shfl(oac[1], 32 + col);
        const float rl = __builtin_amdgcn_rcpf(sm);
        oac *= rl;
        // O^T C-layout: lane col = q, rows d = 4g + rr; keep d < 12
        if (g < 3)
            *(f4*)&XB[q * 12 + g * 4] = oac;
        __syncthreads();
    }

    // ---- logits + log_softmax ----
    if (tid < 128) {
        const f4* xp = (const f4*)&XB[r * 12];
        f4 a0 = xp[0], a1 = xp[1], a2 = xp[2];
        float xr[9] = {a0.x, a0.y, a0.z, a0.w, a1.x, a1.y, a1.z, a1.w, a2.x};
        float lg[Vn];
        #pragma unroll
        for (int v = 0; v < Vn; ++v) {
            float a = bout[v];
            #pragma unroll
            for (int d = 0; d < Dn; ++d) a = fmaf(xr[d], Wout[v * Dn + d], a);
            lg[v] = a;
        }
        float mm = lg[0];
        #pragma unroll
        for (int v = 1; v < Vn; ++v) mm = fmaxf(mm, lg[v]);
        float sum = 0.0f;
        #pragma unroll
        for (int v = 0; v < Vn; ++v)
            sum += __builtin_amdgcn_exp2f((lg[v] - mm) * 1.44269504f);
        const float lse = __builtin_amdgcn_logf(sum) * 0.69314718f + mm;
        float* op = out + ((size_t)b * Sn + r) * Vn;
        #pragma unroll
        for (int v = 0; v < Vn; ++v) op[v] = lg[v] - lse;
    }
}

extern "C" void kernel_launch(void* const* d_in, const int* in_sizes, int n_in,
                              void* d_out, int out_size, void* d_ws, size_t ws_size,
                              hipStream_t stream) {
    const int*   tokens = (const int*)  d_in[0];
    const float* emb    = (const float*)d_in[1];
    const float* Wq     = (const float*)d_in[2];
    const float* bq_    = (const float*)d_in[3];
    const float* Wk     = (const float*)d_in[4];
    const float* Wv     = (const float*)d_in[6];
    const float* bv_    = (const float*)d_in[7];
    const float* Wout   = (const float*)d_in[8];
    const float* bout_  = (const float*)d_in[9];
    float* out = (float*)d_out;
    float* ws  = (float*)d_ws;

    prep_kernel<<<dim3(6), dim3(256), 0, stream>>>(Wq, bq_, Wk, ws);
    bert_kernel<<<dim3(Bn), dim3(512), 0, stream>>>(
        tokens, emb, Wv, bv_, Wout, bout_, ws, out);
}

// Round 6
// 127.989 us; speedup vs baseline: 1.0487x; 1.0487x over previous
//
#include <hip/hip_runtime.h>
#include <math.h>

// B,S,D,V,N_BLOCKS = 4096,128,9,5,4
constexpr int Bn = 4096;
constexpr int Sn = 128;
constexpr int Dn = 9;
constexpr int Vn = 5;
constexpr int NBn = 4;

typedef float f4 __attribute__((ext_vector_type(4)));
typedef _Float16 h8 __attribute__((ext_vector_type(8)));   // MFMA operand type
typedef __fp16   h2 __attribute__((ext_vector_type(2)));
typedef unsigned u4v __attribute__((ext_vector_type(4)));
typedef short s4v __attribute__((ext_vector_type(4)));

// Workspace layout (floats):
//  [it*96 + e*9 + d]  = M'[e][d] = qscale * sum_f Wk[f][e]*Wq[f][d]   (it<4, e,d<9)
//  [it*96 + 81 + d]   = w'[d]    = qscale * sum_f Wk[f][d]*bq[f]
//  [384 + r*9 + d]    = positional encoding PE[r][d]
// Softmax shift invariance: S[q][k] = x_q M x_k + w.x_k (+ per-q consts that
// cancel), so K-side needs NO projection and bk drops out entirely.
constexpr int WS_PE = 384;

// LDS layout (bytes). Row stride 80B = 20 banks (odd multiple of 4) so both
// the 4xb128 row writes and the quad frag reads spread uniformly over all
// eight 4-bank groups.
//  KF [128] rows x 32 fp16 slots [Xh(9)|Xh(9)|Xl(9)|th,tl|z3], stride 40 shorts
//  QF [128] rows x 32 fp16 slots [Yh(9)|Yl(9)|Yh(9)|1,1|z3], Y = M'^T-proj of x
//     One K=32 MFMA yields Xh*Yh + Xh*Yl + Xl*Yh + t (exact to ~2^-22).
//  VF [16][136] fp16 V^T; row 9 = 1.0 (written once) so the PV MFMA also
//     produces the softmax denominator as O^T row 9. Rows 10..15 unwritten.
//  XB [128][12] f32 inter-layer activations, stride 48B
// No-max softmax: scores bounded |s|<~12 in log2 domain; exp2 direct is safe
// (fp16 max 2^15.99) and rcp-normalization restores the exact softmax.
//
// R5 POST-MORTEM: __launch_bounds__(512,8) capped VGPR at 64 -> scratch
// spills (VGPR_Count=32, WRITE_SIZE +8MB). R6: bounds (512,6) -> cap 80,
// 24 waves/CU, and phase-2 restructured for low peak pressure: kfr read
// interleaved into the QK^T MFMA loop (not resident), vf loaded after exp2.
constexpr int KF_OFF = 0;          // 10240
constexpr int QF_OFF = 10240;      // 10240
constexpr int VF_OFF = 20480;      // 16*272 = 4352
constexpr int XB_OFF = 24832;      // 6144
constexpr int SMEM_BYTES = 30976;

static __device__ __forceinline__ void split_hl(const float* v, _Float16* H, _Float16* L) {
    #pragma unroll
    for (int i = 0; i < 9; ++i) {
        _Float16 h = (_Float16)v[i];
        H[i] = h;
        L[i] = (_Float16)(v[i] - (float)h);
    }
}

static __device__ __forceinline__ unsigned pk(_Float16 a, _Float16 b) {
    h2 t; t.x = (__fp16)a; t.y = (__fp16)b;
    return __builtin_bit_cast(unsigned, t);
}

// Store one 32-slot row [X(9)|Y(9)|Z(9)|T0,T1|0,0,0] (4 x b128)
static __device__ __forceinline__ void store_row32(short* rowp,
        const _Float16* X, const _Float16* Y, const _Float16* Z,
        _Float16 T0, _Float16 T1) {
    const _Float16 z0 = (_Float16)0.0f;
    u4v w0 = (u4v){ pk(X[0],X[1]), pk(X[2],X[3]), pk(X[4],X[5]), pk(X[6],X[7]) };
    u4v w1 = (u4v){ pk(X[8],Y[0]), pk(Y[1],Y[2]), pk(Y[3],Y[4]), pk(Y[5],Y[6]) };
    u4v w2 = (u4v){ pk(Y[7],Y[8]), pk(Z[0],Z[1]), pk(Z[2],Z[3]), pk(Z[4],Z[5]) };
    u4v w3 = (u4v){ pk(Z[6],Z[7]), pk(Z[8],T0),   pk(T1,z0),     0u            };
    u4v* qp = (u4v*)rowp;
    qp[0] = w0; qp[1] = w1; qp[2] = w2; qp[3] = w3;
}

static __device__ __forceinline__ h8 read_quad(const short* base, int row, int quad) {
    return *(const h8*)(base + row * 40 + quad * 8);
}

// Tiny prep: M'/w' folds (input-only, shared by all 4096 blocks) + PE table.
__global__ void prep_kernel(const float* __restrict__ Wq, const float* __restrict__ bq,
                            const float* __restrict__ Wk, float* __restrict__ ws)
{
    const float qs = (1.0f / 3.0f) * 1.44269504f;   // 1/sqrt(D) * log2(e)
    const int idx = blockIdx.x * 256 + threadIdx.x;
    if (idx < 360) {
        const int it = idx / 90, j = idx % 90;
        const float* wq = Wq + it * 81;
        const float* wk = Wk + it * 81;
        float acc = 0.0f;
        if (j < 81) {
            const int e = j / 9, d = j % 9;
            #pragma unroll
            for (int f = 0; f < 9; ++f) acc = fmaf(wk[f * 9 + e], wq[f * 9 + d], acc);
        } else {
            const int d = j - 81;
            const float* bqp = bq + it * 9;
            #pragma unroll
            for (int f = 0; f < 9; ++f) acc = fmaf(wk[f * 9 + d], bqp[f], acc);
        }
        ws[it * 96 + j] = acc * qs;
    } else if (idx < 360 + Sn * Dn) {
        const int j = idx - 360;
        const int r = j / 9, d = j % 9;
        const float inv_freq[Dn] = {
            1.0f, 1.0f, 0.1291549665f, 0.1291549665f, 0.0166810054f,
            0.0166810054f, 0.0021544347f, 0.0021544347f, 0.0002782559f };
        const float a = (float)r * inv_freq[d];
        ws[WS_PE + j] = (d & 1) ? cosf(a) : sinf(a);
    }
}

// One block = one batch, 8 waves. Phase 1 (per row r = tid&127, quarter
// tid>>7): q0 stages raw-X K rows + bias-fold t, q1 projects Y = M'^T x,
// q2/q3 project V columns. Phase 2: wave w owns q-tile w: S^T via one
// 3-term MFMA per key-tile, exp2 direct (no max), denominator from the PV
// ones-row, O^T = V^T.P^T fp16 (4 MFMAs).
__global__ __launch_bounds__(512, 6) void bert_kernel(
    const int*   __restrict__ tokens,
    const float* __restrict__ emb,
    const float* __restrict__ Wv, const float* __restrict__ bv,
    const float* __restrict__ Wout, const float* __restrict__ bout,
    const float* __restrict__ wsp,
    float*       __restrict__ out)
{
    __shared__ __align__(16) char smem[SMEM_BYTES];
    short* KF = (short*)(smem + KF_OFF);
    short* QF = (short*)(smem + QF_OFF);
    short* VF = (short*)(smem + VF_OFF);
    float* XB = (float*)(smem + XB_OFF);

    const int b   = blockIdx.x;
    const int tid = threadIdx.x;         // 0..511
    const int t   = tid & 63;
    const int w   = tid >> 6;            // wave 0..7
    const int col = t & 15;
    const int g   = t >> 4;
    const int q4  = tid >> 7;            // phase-1 quarter 0..3
    const int r   = tid & 127;           // phase-1 row
    const float* MP = wsp;               // [4][96] M'/w'
    const float* PE = wsp + WS_PE;       // [128][9]

    // ---- stage 0: embed + positional encoding -> XB; VF ones row ----
    if (tid < 128) {
        const int tok = tokens[b * Sn + r];
        float xr[9];
        #pragma unroll
        for (int d = 0; d < Dn; ++d)
            xr[d] = emb[tok * Dn + d] + PE[r * 9 + d];
        f4* xp = (f4*)&XB[r * 12];
        xp[0] = (f4){xr[0], xr[1], xr[2], xr[3]};
        xp[1] = (f4){xr[4], xr[5], xr[6], xr[7]};
        xp[2] = (f4){xr[8], 0.0f, 0.0f, 0.0f};
    } else if (tid < 256) {
        VF[9 * 136 + r] = (short)0x3C00;   // fp16 1.0 — persists across layers
    }
    __syncthreads();

    #pragma unroll 1
    for (int it = 0; it < NBn; ++it) {
        // ---- phase 1: staging, split 4-ways per row ----
        {
            const f4* xp = (const f4*)&XB[r * 12];
            f4 a0 = xp[0], a1 = xp[1], a2 = xp[2];
            float x[9] = {a0.x, a0.y, a0.z, a0.w, a1.x, a1.y, a1.z, a1.w, a2.x};
            const float* wv  = Wv + it * 81;
            const float* bvi = bv + it * 9;
            const float* mp  = MP + it * 96;
            if (q4 == 0) {
                float tb = 0.0f;                      // t_k = w'.x (bias fold)
                #pragma unroll
                for (int d = 0; d < Dn; ++d) tb = fmaf(x[d], mp[81 + d], tb);
                _Float16 H[9], L[9];
                split_hl(x, H, L);
                _Float16 th = (_Float16)tb;
                _Float16 tl = (_Float16)(tb - (float)th);
                store_row32(KF + r * 40, H, H, L, th, tl);   // [Xh|Xh|Xl|th,tl]
            } else if (q4 == 1) {
                float y[9];                           // y = M'^T-fold of x (pre-scaled)
                #pragma unroll
                for (int e = 0; e < Dn; ++e) {
                    float a = 0.0f;
                    #pragma unroll
                    for (int d = 0; d < Dn; ++d) a = fmaf(x[d], mp[e * 9 + d], a);
                    y[e] = a;
                }
                _Float16 H[9], L[9];
                split_hl(y, H, L);
                store_row32(QF + r * 40, H, L, H,
                            (_Float16)1.0f, (_Float16)1.0f);  // [Yh|Yl|Yh|1,1]
            } else if (q4 == 2) {
                #pragma unroll
                for (int e = 0; e < 5; ++e) {
                    float av = bvi[e];
                    #pragma unroll
                    for (int d = 0; d < Dn; ++d) av = fmaf(x[d], wv[e * 9 + d], av);
                    VF[e * 136 + r] = __builtin_bit_cast(short, (_Float16)av);
                }
            } else {
                #pragma unroll
                for (int e = 5; e < Dn; ++e) {
                    float av = bvi[e];
                    #pragma unroll
                    for (int d = 0; d < Dn; ++d) av = fmaf(x[d], wv[e * 9 + d], av);
                    VF[e * 136 + r] = __builtin_bit_cast(short, (_Float16)av);
                }
            }
        }
        __syncthreads();

        // ---- phase 2: wave w owns q-tile w ----
        const int q = w * 16 + col;
        h8 bq3 = read_quad(QF, q, g);

        // QK^T: kfr read interleaved per k-tile (not resident across the
        // loop) — peak pressure ~ acc(32) + 2-3 in-flight kfr.
        f4 acc[8];
        #pragma unroll
        for (int kt = 0; kt < 8; ++kt) {
            h8 kfr = read_quad(KF, kt * 16 + col, g);
            acc[kt] = __builtin_amdgcn_mfma_f32_16x16x32_f16(kfr, bq3, (f4)(0.0f), 0, 0, 0);
        }

        // lane holds S^T[key = kt*16 + 4g + rr][q] (log2 domain); exp2 direct.
        #pragma unroll
        for (int kt = 0; kt < 8; ++kt)
            #pragma unroll
            for (int rr = 0; rr < 4; ++rr)
                acc[kt][rr] = __builtin_amdgcn_exp2f(acc[kt][rr]);

        // V^T A-frags (loaded only now — live only through PV):
        // slot (g,j) <-> key 16*(2s+(j>>2))+4g+(j&3)
        // P B-frags: slot j=0..3 -> (kt=2s, rr=j); j=4..7 -> (kt=2s+1, rr=j&3)
        f4 oac = (f4)(0.0f);
        #pragma unroll
        for (int s = 0; s < 4; ++s) {
            const short* p0 = VF + col * 136 + 32 * s + 4 * g;
            s4v va = *(const s4v*)p0;
            s4v vb = *(const s4v*)(p0 + 16);
            h8 vf = __builtin_bit_cast(h8,
                __builtin_shufflevector(va, vb, 0, 1, 2, 3, 4, 5, 6, 7));
            u4v up = (u4v){
                __builtin_bit_cast(unsigned, __builtin_amdgcn_cvt_pkrtz(acc[2*s][0],   acc[2*s][1])),
                __builtin_bit_cast(unsigned, __builtin_amdgcn_cvt_pkrtz(acc[2*s][2],   acc[2*s][3])),
                __builtin_bit_cast(unsigned, __builtin_amdgcn_cvt_pkrtz(acc[2*s+1][0], acc[2*s+1][1])),
                __builtin_bit_cast(unsigned, __builtin_amdgcn_cvt_pkrtz(acc[2*s+1][2], acc[2*s+1][3])) };
            oac = __builtin_amdgcn_mfma_f32_16x16x32_f16(vf, __builtin_bit_cast(h8, up), oac, 0, 0, 0);
        }
        // denominator: O^T row 9 = sum_k P[k][q], held by lane 32+q, reg 1
        const float sm = __shfl(oac[1], 32 + col);
        const float rl = __builtin_amdgcn_rcpf(sm);
        oac *= rl;
        // O^T C-layout: lane col = q, rows d = 4g + rr; keep d < 12
        if (g < 3)
            *(f4*)&XB[q * 12 + g * 4] = oac;
        __syncthreads();
    }

    // ---- logits + log_softmax ----
    if (tid < 128) {
        const f4* xp = (const f4*)&XB[r * 12];
        f4 a0 = xp[0], a1 = xp[1], a2 = xp[2];
        float xr[9] = {a0.x, a0.y, a0.z, a0.w, a1.x, a1.y, a1.z, a1.w, a2.x};
        float lg[Vn];
        #pragma unroll
        for (int v = 0; v < Vn; ++v) {
            float a = bout[v];
            #pragma unroll
            for (int d = 0; d < Dn; ++d) a = fmaf(xr[d], Wout[v * Dn + d], a);
            lg[v] = a;
        }
        float mm = lg[0];
        #pragma unroll
        for (int v = 1; v < Vn; ++v) mm = fmaxf(mm, lg[v]);
        float sum = 0.0f;
        #pragma unroll
        for (int v = 0; v < Vn; ++v)
            sum += __builtin_amdgcn_exp2f((lg[v] - mm) * 1.44269504f);
        const float lse = __builtin_amdgcn_logf(sum) * 0.69314718f + mm;
        float* op = out + ((size_t)b * Sn + r) * Vn;
        #pragma unroll
        for (int v = 0; v < Vn; ++v) op[v] = lg[v] - lse;
    }
}

extern "C" void kernel_launch(void* const* d_in, const int* in_sizes, int n_in,
                              void* d_out, int out_size, void* d_ws, size_t ws_size,
                              hipStream_t stream) {
    const int*   tokens = (const int*)  d_in[0];
    const float* emb    = (const float*)d_in[1];
    const float* Wq     = (const float*)d_in[2];
    const float* bq_    = (const float*)d_in[3];
    const float* Wk     = (const float*)d_in[4];
    const float* Wv     = (const float*)d_in[6];
    const float* bv_    = (const float*)d_in[7];
    const float* Wout   = (const float*)d_in[8];
    const float* bout_  = (const float*)d_in[9];
    float* out = (float*)d_out;
    float* ws  = (float*)d_ws;

    prep_kernel<<<dim3(6), dim3(256), 0, stream>>>(Wq, bq_, Wk, ws);
    bert_kernel<<<dim3(Bn), dim3(512), 0, stream>>>(
        tokens, emb, Wv, bv_, Wout, bout_, ws, out);
}